// Round 11
// baseline (1625.651 us; speedup 1.0000x reference)
//
#include <hip/hip_runtime.h>
#include <cstddef>
#include <cstdint>

// Problem constants
#define BB   64
#define NN   512
#define BN   (BB*NN)          // 32768
#define HBN  16384            // nodes per half
#define EE   524288
#define DA   70
#define DE   14
#define DH   200
#define DI   6
#define T_SCALE 0.07071067811865475f   // sqrt(1/200)

typedef __attribute__((ext_vector_type(8))) short short8;
typedef __attribute__((ext_vector_type(4))) float f32x4;

__device__ __forceinline__ short f2bf(float x) {
    union { float f; unsigned u; } v; v.f = x;
    const unsigned r = v.u + 0x7FFFu + ((v.u >> 16) & 1u);   // RNE
    return (short)(r >> 16);
}
__device__ __forceinline__ float bf2f(short s) {
    union { unsigned u; float f; } v;
    v.u = ((unsigned)(unsigned short)s) << 16;
    return v.f;
}

// ---------------------------------------------------------------------------
// Kernel 1: per-node  h = layernorm(relu(atom @ W_atom))
// ---------------------------------------------------------------------------
__global__ __launch_bounds__(256) void node_kernel(
    const float* __restrict__ atom1, const float* __restrict__ atom2,
    const float* __restrict__ W_atom,
    const float* __restrict__ ln_g, const float* __restrict__ ln_b,
    float* __restrict__ h1, float* __restrict__ h2)
{
    const int side = blockIdx.y;
    const float* atom = side ? atom2 : atom1;
    float* h = side ? h2 : h1;
    const int node0 = blockIdx.x * 4;
    const int tid = threadIdx.x;

    __shared__ float arow[4][DA];
    __shared__ float vals[4][DH];

    for (int i = tid; i < 4*DA; i += 256) {
        const int n = i / DA, k = i % DA;
        arow[n][k] = atom[(size_t)(node0+n)*DA + k];
    }
    __syncthreads();

    if (tid < DH) {
        float a0 = 0.f, a1 = 0.f, a2 = 0.f, a3 = 0.f;
        #pragma unroll 7
        for (int k = 0; k < DA; k++) {
            const float w = W_atom[k*DH + tid];
            a0 += arow[0][k]*w; a1 += arow[1][k]*w;
            a2 += arow[2][k]*w; a3 += arow[3][k]*w;
        }
        vals[0][tid] = fmaxf(a0, 0.f);
        vals[1][tid] = fmaxf(a1, 0.f);
        vals[2][tid] = fmaxf(a2, 0.f);
        vals[3][tid] = fmaxf(a3, 0.f);
    }
    __syncthreads();

    const int wv = tid >> 6, lane = tid & 63;
    float v0 = vals[wv][lane];
    float v1 = vals[wv][64+lane];
    float v2 = vals[wv][128+lane];
    float v3 = (lane < 8) ? vals[wv][192+lane] : 0.0f;
    float s  = v0+v1+v2+v3;
    float s2 = v0*v0+v1*v1+v2*v2+v3*v3;
    #pragma unroll
    for (int off = 1; off < 64; off <<= 1) {
        s  += __shfl_xor(s,  off, 64);
        s2 += __shfl_xor(s2, off, 64);
    }
    const float mean = s * (1.0f/DH);
    const float var  = s2 * (1.0f/DH) - mean*mean;
    const float rstd = rsqrtf(var + 1e-5f);
    const size_t base = (size_t)(node0+wv)*DH;
    h[base + lane]       = ln_g[lane]     *(v0-mean)*rstd + ln_b[lane];
    h[base + 64 + lane]  = ln_g[64+lane]  *(v1-mean)*rstd + ln_b[64+lane];
    h[base + 128 + lane] = ln_g[128+lane] *(v2-mean)*rstd + ln_b[128+lane];
    if (lane < 8)
        h[base + 192 + lane] = ln_g[192+lane]*(v3-mean)*rstd + ln_b[192+lane];
}

// ---------------------------------------------------------------------------
// Counting sort by dst: hist -> scan(+sentinel) -> scatter (rank only)
// ---------------------------------------------------------------------------
__global__ __launch_bounds__(256) void hist_kernel(
    const int* __restrict__ edst1, const int* __restrict__ edst2,
    int* __restrict__ deg1, int* __restrict__ deg2)
{
    const int e = blockIdx.x*256 + threadIdx.x;
    atomicAdd(&deg1[edst1[e]], 1);
    atomicAdd(&deg2[edst2[e]], 1);
}

__global__ __launch_bounds__(1024) void scan_kernel(
    const int* __restrict__ deg1, const int* __restrict__ deg2,
    int* __restrict__ start1, int* __restrict__ start2,
    int* __restrict__ cursor1, int* __restrict__ cursor2)
{
    const int side = blockIdx.x;
    const int* deg   = side ? deg2 : deg1;
    int* start  = side ? start2 : start1;
    int* cursor = side ? cursor2 : cursor1;

    __shared__ int part[1024];
    const int t = threadIdx.x;
    const int base = t * 32;
    int local[32];
    int sum = 0;
    #pragma unroll
    for (int i = 0; i < 32; i++) { local[i] = deg[base+i]; sum += local[i]; }
    part[t] = sum;
    __syncthreads();
    for (int off = 1; off < 1024; off <<= 1) {
        int v = (t >= off) ? part[t-off] : 0;
        __syncthreads();
        part[t] += v;
        __syncthreads();
    }
    int run = part[t] - sum;   // exclusive
    #pragma unroll
    for (int i = 0; i < 32; i++) {
        start[base+i] = run;
        cursor[base+i] = run;
        run += local[i];
    }
    if (t == 1023) start[BN] = run;   // sentinel == EE
}

__global__ __launch_bounds__(256) void scatter_kernel(
    const int* __restrict__ edst1, const int* __restrict__ edst2,
    int* __restrict__ cursor1, int* __restrict__ cursor2,
    int* __restrict__ rank1, int* __restrict__ rank2)
{
    const int e = blockIdx.x*256 + threadIdx.x;
    {
        const int d = edst1[e];
        rank1[e] = atomicAdd(&cursor1[d], 1);
    }
    {
        const int d = edst2[e];
        rank2[e] = atomicAdd(&cursor2[d], 1);
    }
}

// ---------------------------------------------------------------------------
// featgen: per-edge feature row (rank-ordered) -> featH[rank][32] bf16
//   k 0..13 = ef, 14..29 = rbf, 30 = 1.0 (bias hook), 31 = 0
// ---------------------------------------------------------------------------
__global__ __launch_bounds__(256) void featgen_kernel(
    const float* __restrict__ efeat1, const float* __restrict__ efeat2,
    const int* __restrict__ esrc1, const int* __restrict__ esrc2,
    const int* __restrict__ edst1, const int* __restrict__ edst2,
    const float* __restrict__ coords1, const float* __restrict__ coords2,
    const int* __restrict__ rank1, const int* __restrict__ rank2,
    short* __restrict__ featH1, short* __restrict__ featH2)
{
    const int side = blockIdx.y;
    const float* ef     = side ? efeat2  : efeat1;
    const int*   esrc   = side ? esrc2   : esrc1;
    const int*   edst   = side ? edst2   : edst1;
    const float* coords = side ? coords2 : coords1;
    const int*   rank   = side ? rank2   : rank1;
    short* featH = side ? featH2 : featH1;

    const int e = blockIdx.x*256 + threadIdx.x;
    const int src = esrc[e], dst = edst[e];

    short f[32];
    #pragma unroll
    for (int k = 0; k < 14; k++) f[k] = f2bf(ef[(size_t)e*DE + k]);

    const float dx = coords[src*3+0] - coords[dst*3+0];
    const float dy = coords[src*3+1] - coords[dst*3+1];
    const float dz = coords[src*3+2] - coords[dst*3+2];
    const float dist = sqrtf(dx*dx + dy*dy + dz*dz + 1e-12f);
    #pragma unroll
    for (int k = 0; k < 16; k++) {
        const float t = 3.2f*dist - 1.0666666667f*(float)k;
        f[14+k] = f2bf(__expf(-t*t));
    }
    f[30] = f2bf(1.0f);
    f[31] = 0;

    short* out = featH + (size_t)rank[e]*32;
    #pragma unroll
    for (int q = 0; q < 4; q++)
        *(short8*)&out[q*8] = *(short8*)&f[q*8];
}

// ---------------------------------------------------------------------------
// prep_wt: build WT[208][32] hi/lo for the edge projection.
// ---------------------------------------------------------------------------
__global__ __launch_bounds__(256) void prep_wt_kernel(
    const float* __restrict__ W_edge, const float* __restrict__ W_rbf,
    const float* __restrict__ b_rbf,
    short* __restrict__ WTH, short* __restrict__ WTL)
{
    const int idx = blockIdx.x*256 + threadIdx.x;
    if (idx >= 208*32) return;
    const int c = idx >> 5, k = idx & 31;
    float v = 0.f;
    if (c < 100) {
        if (k < 14) v = W_edge[k*100 + c];
    } else if (c < 200) {
        const int cc = c - 100;
        if (k >= 14 && k < 30) v = W_rbf[(k-14)*100 + cc];
        else if (k == 30) v = b_rbf[cc];
    }
    const short hi = f2bf(v);
    WTH[idx] = hi;
    WTL[idx] = f2bf(v - bf2f(hi));
}

// ---------------------------------------------------------------------------
// gather_mfma: per 4-node block. x = relu(feat @ W) via MFMA (W frags in
// registers, hi+lo), LN stats computed in-register from the same x,
// run-merged LDS-atomic segment sum into per-node accumulators.
// Wave wv owns 16-edge tiles t0 = wv*16, wv*16+64, ... (4-way partition).
// ---------------------------------------------------------------------------
__global__ __launch_bounds__(256) void gather_mfma(
    const short* __restrict__ featH1, const short* __restrict__ featH2,
    const int* __restrict__ start1, const int* __restrict__ start2,
    const short* __restrict__ WTH, const short* __restrict__ WTL,
    const float* __restrict__ ln_g, const float* __restrict__ ln_b,
    float* __restrict__ h1, float* __restrict__ h2)
{
    const int side = blockIdx.y;
    const short* feat = side ? featH2 : featH1;
    const int* start  = side ? start2 : start1;
    float* h = side ? h2 : h1;

    const int nb = blockIdx.x * 4;

    __shared__ float accum[4][216];   // stride 216 -> node-planes hit distinct banks
    __shared__ float musum[4];

    const int tid = threadIdx.x;
    const int wv = tid >> 6, lane = tid & 63;
    const int arow = lane & 15, aq = lane >> 4;

    for (int i = tid; i < 4*216; i += 256) ((float*)accum)[i] = 0.f;
    if (tid < 4) musum[tid] = 0.f;

    // W fragments in registers (loop-invariant)
    short8 wh[13], wl[13];
    #pragma unroll
    for (int nt = 0; nt < 13; nt++) {
        wh[nt] = *(const short8*)&WTH[(nt*16 + arow)*32 + aq*8];
        wl[nt] = *(const short8*)&WTL[(nt*16 + arow)*32 + aq*8];
    }

    const int s0 = start[nb],   s1 = start[nb+1];
    const int s2n = start[nb+2], s3 = start[nb+3], s4 = start[nb+4];
    const int cnt = s4 - s0;
    __syncthreads();

    // FIX (R10 bug): partition 16-edge tiles across the 4 waves.
    for (int t0 = wv*16; t0 < cnt; t0 += 64) {
        const short8 a = *(const short8*)&feat[(size_t)(s0 + t0 + arow)*32 + aq*8];
        f32x4 acc[13];
        #pragma unroll
        for (int nt = 0; nt < 13; nt++) {
            acc[nt] = (f32x4){0.f,0.f,0.f,0.f};
            acc[nt] = __builtin_amdgcn_mfma_f32_16x16x32_bf16(a, wh[nt], acc[nt], 0, 0, 0);
            acc[nt] = __builtin_amdgcn_mfma_f32_16x16x32_bf16(a, wl[nt], acc[nt], 0, 0, 0);
        }
        // relu + per-row stats (rows = t0 + aq*4 + r)
        float sr[4] = {0.f,0.f,0.f,0.f}, s2r[4] = {0.f,0.f,0.f,0.f};
        #pragma unroll
        for (int nt = 0; nt < 13; nt++) {
            #pragma unroll
            for (int r = 0; r < 4; r++) {
                const float v = fmaxf(acc[nt][r], 0.f);
                acc[nt][r] = v;
                sr[r] += v; s2r[r] += v*v;
            }
        }
        #pragma unroll
        for (int off = 1; off < 16; off <<= 1) {
            #pragma unroll
            for (int r = 0; r < 4; r++) {
                sr[r]  += __shfl_xor(sr[r],  off, 64);
                s2r[r] += __shfl_xor(s2r[r], off, 64);
            }
        }
        float rstd[4], mus[4]; int nid[4];
        #pragma unroll
        for (int r = 0; r < 4; r++) {
            const int row = t0 + aq*4 + r;
            const bool valid = row < cnt;
            const int e = s0 + row;
            const float mean = sr[r] * (1.0f/DH);
            const float var  = s2r[r] * (1.0f/DH) - mean*mean;
            const float rs = rsqrtf(var + 1e-5f);
            rstd[r] = valid ? rs : 0.f;
            mus[r]  = valid ? mean*rs : 0.f;
            nid[r] = (e >= s1) + (e >= s2n) + (e >= s3);
        }
        // run-merged segment add per N-tile
        #pragma unroll
        for (int nt = 0; nt < 13; nt++) {
            const int col = nt*16 + arow;
            const float v0 = rstd[0]*acc[nt][0];
            const float v1 = rstd[1]*acc[nt][1];
            const float v2 = rstd[2]*acc[nt][2];
            const float v3 = rstd[3]*acc[nt][3];
            float cur = v0;
            if (nid[1] != nid[0]) { atomicAdd(&accum[nid[0]][col], cur); cur = v1; }
            else cur += v1;
            if (nid[2] != nid[1]) { atomicAdd(&accum[nid[1]][col], cur); cur = v2; }
            else cur += v2;
            if (nid[3] != nid[2]) { atomicAdd(&accum[nid[2]][col], cur); cur = v3; }
            else cur += v3;
            atomicAdd(&accum[nid[3]][col], cur);
        }
        if (arow == 0) {
            float cur = mus[0];
            if (nid[1] != nid[0]) { atomicAdd(&musum[nid[0]], cur); cur = mus[1]; }
            else cur += mus[1];
            if (nid[2] != nid[1]) { atomicAdd(&musum[nid[1]], cur); cur = mus[2]; }
            else cur += mus[2];
            if (nid[3] != nid[2]) { atomicAdd(&musum[nid[2]], cur); cur = mus[3]; }
            else cur += mus[3];
            atomicAdd(&musum[nid[3]], cur);
        }
    }
    __syncthreads();

    // final: wave wv updates node nb+wv
    const int node = nb + wv;
    const float dgf = (float)(start[node+1] - start[node]);
    const float mu = musum[wv];
    const size_t base = (size_t)node * DH;
    h[base + lane]       += ln_g[lane]     *(accum[wv][lane]     - mu) + dgf*ln_b[lane];
    h[base + 64 + lane]  += ln_g[64+lane]  *(accum[wv][64+lane]  - mu) + dgf*ln_b[64+lane];
    h[base + 128 + lane] += ln_g[128+lane] *(accum[wv][128+lane] - mu) + dgf*ln_b[128+lane];
    if (lane < 8)
        h[base + 192 + lane] += ln_g[192+lane]*(accum[wv][192+lane] - mu) + dgf*ln_b[192+lane];
}

// ---------------------------------------------------------------------------
// cvt (per half): h fp32 -> hb hi/lo [16384][224] rows + hbT hi/lo [32][224][512]
// ---------------------------------------------------------------------------
__global__ __launch_bounds__(256) void cvt_kernel(
    const float* __restrict__ h1, const float* __restrict__ h2, const int half,
    short* __restrict__ hbH1, short* __restrict__ hbL1,
    short* __restrict__ hbH2, short* __restrict__ hbL2,
    short* __restrict__ hTH1, short* __restrict__ hTL1,
    short* __restrict__ hTH2, short* __restrict__ hTL2)
{
    const int side = blockIdx.y;
    const float* h = side ? h2 : h1;
    short* hbH = side ? hbH2 : hbH1;
    short* hbL = side ? hbL2 : hbL1;
    short* hTH = side ? hTH2 : hTH1;
    short* hTL = side ? hTL2 : hTL1;

    const int nl0 = blockIdx.x * 64;          // local node
    const int bl = nl0 >> 9, m0 = nl0 & 511;
    const int ng0 = half*HBN + nl0;

    __shared__ short tH[64][226];
    __shared__ short tL[64][226];
    const int tid = threadIdx.x;
    for (int i = tid; i < 64*224; i += 256) {
        const int r = i / 224, c = i - r*224;
        const float v = (c < DH) ? h[(size_t)(ng0+r)*DH + c] : 0.f;
        const short hi = f2bf(v);
        const short lo = f2bf(v - bf2f(hi));
        tH[r][c] = hi; tL[r][c] = lo;
        hbH[(size_t)(nl0+r)*224 + c] = hi;
        hbL[(size_t)(nl0+r)*224 + c] = lo;
    }
    __syncthreads();
    for (int i = tid; i < 224*64; i += 256) {
        const int c = i >> 6, m = i & 63;
        const size_t o = ((size_t)bl*224 + c)*NN + m0 + m;
        hTH[o] = tH[m][c];
        hTL[o] = tL[m][c];
    }
}

// ---------------------------------------------------------------------------
// prep_w: W_down[400][200] -> WbTHI/LO[208][448] (transposed, padded, split)
// ---------------------------------------------------------------------------
__global__ __launch_bounds__(256) void prep_w_kernel(
    const float* __restrict__ W_down,
    short* __restrict__ WbTHI, short* __restrict__ WbTLO)
{
    const int idx = blockIdx.x*256 + threadIdx.x;
    if (idx >= 208*448) return;
    const int c = idx / 448, kk = idx - c*448;
    float v = 0.f;
    if (c < 200) {
        if (kk < 200) v = W_down[(size_t)kk*DH + c];
        else if (kk >= 224 && kk < 424) v = W_down[(size_t)(200 + kk - 224)*DH + c];
    }
    const short hi = f2bf(v);
    WbTHI[idx] = hi;
    WbTLO[idx] = f2bf(v - bf2f(hi));
}

// ---------------------------------------------------------------------------
// Fused attention v3: 16 Q-rows per block, 4 waves split 32 key-tiles;
// K/V streamed from global (L2); 3 barriers per block.
// ---------------------------------------------------------------------------
__global__ __launch_bounds__(256, 4) void attn_kernel(
    const short* __restrict__ QH, const short* __restrict__ QL,
    const short* __restrict__ KH, const short* __restrict__ KL,
    const short* __restrict__ VTH, const short* __restrict__ VTL,
    short* __restrict__ cb)
{
    const int b = blockIdx.y;                 // half-local batch
    const int q0 = blockIdx.x * 16;
    const short* Qh = QH + (size_t)b*NN*224;
    const short* Ql = QL + (size_t)b*NN*224;
    const short* Kh = KH + (size_t)b*NN*224;
    const short* Kl = KL + (size_t)b*NN*224;
    const short* Vh = VTH + (size_t)b*224*NN;
    const short* Vl = VTL + (size_t)b*224*NN;

    __shared__ short pb[16*520];              // 16.3 KB P bf16
    __shared__ float sm_[4][16];
    __shared__ float ss_[4][16];

    const int tid = threadIdx.x;
    const int wv = tid >> 6, lane = tid & 63;
    const int arow = lane & 15, aq = lane >> 4;

    const int qrow = q0 + arow;
    short8 qfh[7], qfl[7];
    #pragma unroll
    for (int k = 0; k < 7; k++) {
        qfh[k] = *(const short8*)&Qh[(size_t)qrow*224 + k*32 + aq*8];
        qfl[k] = *(const short8*)&Ql[(size_t)qrow*224 + k*32 + aq*8];
    }

    f32x4 acc[8];
    #pragma unroll
    for (int t = 0; t < 8; t++) acc[t] = (f32x4){0.f,0.f,0.f,0.f};

    #pragma unroll
    for (int t = 0; t < 8; t++) {
        const size_t kb = (size_t)((wv*8 + t)*16 + arow)*224;
        #pragma unroll
        for (int k = 0; k < 7; k++) {
            const short8 bh = *(const short8*)&Kh[kb + k*32 + aq*8];
            const short8 bl = *(const short8*)&Kl[kb + k*32 + aq*8];
            acc[t] = __builtin_amdgcn_mfma_f32_16x16x32_bf16(qfh[k], bh, acc[t], 0, 0, 0);
            acc[t] = __builtin_amdgcn_mfma_f32_16x16x32_bf16(qfh[k], bl, acc[t], 0, 0, 0);
            acc[t] = __builtin_amdgcn_mfma_f32_16x16x32_bf16(qfl[k], bh, acc[t], 0, 0, 0);
        }
    }

    float mr[4], sr[4], iv[4];
    #pragma unroll
    for (int r = 0; r < 4; r++) {
        float m = -1e30f;
        #pragma unroll
        for (int t = 0; t < 8; t++) {
            acc[t][r] *= T_SCALE;
            m = fmaxf(m, acc[t][r]);
        }
        m = fmaxf(m, __shfl_xor(m, 1, 64));
        m = fmaxf(m, __shfl_xor(m, 2, 64));
        m = fmaxf(m, __shfl_xor(m, 4, 64));
        m = fmaxf(m, __shfl_xor(m, 8, 64));
        mr[r] = m;
    }
    if (arow == 0) {
        #pragma unroll
        for (int r = 0; r < 4; r++) sm_[wv][aq*4+r] = mr[r];
    }
    __syncthreads();
    #pragma unroll
    for (int r = 0; r < 4; r++) {
        const int row = aq*4 + r;
        const float M = fmaxf(fmaxf(sm_[0][row], sm_[1][row]),
                              fmaxf(sm_[2][row], sm_[3][row]));
        float s = 0.f;
        #pragma unroll
        for (int t = 0; t < 8; t++) {
            const float e = __expf(acc[t][r] - M);
            acc[t][r] = e;
            s += e;
        }
        s += __shfl_xor(s, 1, 64);
        s += __shfl_xor(s, 2, 64);
        s += __shfl_xor(s, 4, 64);
        s += __shfl_xor(s, 8, 64);
        sr[r] = s;
    }
    if (arow == 0) {
        #pragma unroll
        for (int r = 0; r < 4; r++) ss_[wv][aq*4+r] = sr[r];
    }
    __syncthreads();
    #pragma unroll
    for (int r = 0; r < 4; r++) {
        const int row = aq*4 + r;
        iv[r] = 1.0f / (ss_[0][row] + ss_[1][row] + ss_[2][row] + ss_[3][row]);
    }

    #pragma unroll
    for (int t = 0; t < 8; t++) {
        const int col = (wv*8 + t)*16 + arow;
        #pragma unroll
        for (int r = 0; r < 4; r++)
            pb[(aq*4 + r)*520 + col] = f2bf(acc[t][r] * iv[r]);
    }
    __syncthreads();

    const int nbase = (wv == 0) ? 0 : 3*wv + 1;
    const int ncnt  = (wv == 0) ? 4 : 3;
    f32x4 pacc[4];
    #pragma unroll
    for (int t = 0; t < 4; t++) pacc[t] = (f32x4){0.f,0.f,0.f,0.f};

    for (int k0 = 0; k0 < NN; k0 += 32) {
        const short8 a = *(const short8*)&pb[arow*520 + k0 + aq*8];
        #pragma unroll
        for (int t = 0; t < 4; t++) {
            if (t < ncnt) {
                const size_t vb = (size_t)((nbase+t)*16 + arow)*NN + k0 + aq*8;
                const short8 bh = *(const short8*)&Vh[vb];
                const short8 bl = *(const short8*)&Vl[vb];
                pacc[t] = __builtin_amdgcn_mfma_f32_16x16x32_bf16(a, bh, pacc[t], 0, 0, 0);
                pacc[t] = __builtin_amdgcn_mfma_f32_16x16x32_bf16(a, bl, pacc[t], 0, 0, 0);
            }
        }
    }

    #pragma unroll
    for (int t = 0; t < 4; t++) {
        if (t < ncnt) {
            const int col = (nbase+t)*16 + arow;
            #pragma unroll
            for (int r = 0; r < 4; r++) {
                const int row = q0 + aq*4 + r;
                const short v = (col < DH) ? f2bf(pacc[t][r]) : (short)0;
                cb[((size_t)b*NN + row)*224 + col] = v;
            }
        }
    }
    if (wv == 3) {
        const int col = 208 + arow;
        #pragma unroll
        for (int r = 0; r < 4; r++) {
            const int row = q0 + aq*4 + r;
            cb[((size_t)b*NN + row)*224 + col] = 0;
        }
    }
}

// ---------------------------------------------------------------------------
// down (per half, MFMA, split-W): relu([hb|cb] @ W_down) + degree_table -> hsg
// ---------------------------------------------------------------------------
__global__ __launch_bounds__(256) void down_mfma(
    const short* __restrict__ hbH1, const short* __restrict__ hbH2,
    const short* __restrict__ cb1, const short* __restrict__ cb2,
    const int* __restrict__ deg1, const int* __restrict__ deg2,
    const short* __restrict__ WbTH, const short* __restrict__ WbTL,
    const float* __restrict__ degree_table,
    float* __restrict__ hsg1, float* __restrict__ hsg2, const int half)
{
    const int side = blockIdx.y;
    const short* X0 = side ? hbH2 : hbH1;
    const short* X1 = side ? cb2 : cb1;
    const int*   dgp = side ? deg2 : deg1;
    float* hsg = side ? hsg2 : hsg1;

    const int nl0 = blockIdx.x * 64;
    const int ng0 = half*HBN + nl0;
    const int b = ng0 >> 9;

    __shared__ short As[64*40];
    __shared__ short BsH[208*40];
    __shared__ short BsL[208*40];
    __shared__ float part[208];

    const int tid = threadIdx.x;
    const int wv = tid >> 6, lane = tid & 63;
    const int arow = lane & 15, aq = lane >> 4;

    if (tid < 208) part[tid] = 0.f;

    f32x4 acc[13];
    #pragma unroll
    for (int t = 0; t < 13; t++) acc[t] = (f32x4){0.f,0.f,0.f,0.f};

    const int sr = tid >> 2, sc = (tid & 3) * 8;

    for (int phase = 0; phase < 2; phase++) {
        const short* X = phase ? X1 : X0;
        for (int k0 = 0; k0 < 224; k0 += 32) {
            __syncthreads();
            *(short8*)&As[sr*40 + sc] =
                *(const short8*)&X[(size_t)(nl0+sr)*224 + k0 + sc];
            const int kkg = phase*224 + k0;
            #pragma unroll
            for (int pass = 0; pass < 4; pass++) {
                const int f = pass*256 + tid;
                if (f < 832) {
                    const int d = f >> 2, cc = (f & 3) * 8;
                    *(short8*)&BsH[d*40 + cc] = *(const short8*)&WbTH[(size_t)d*448 + kkg + cc];
                    *(short8*)&BsL[d*40 + cc] = *(const short8*)&WbTL[(size_t)d*448 + kkg + cc];
                }
            }
            __syncthreads();
            const short8 a = *(const short8*)&As[(16*wv + arow)*40 + aq*8];
            #pragma unroll
            for (int t = 0; t < 13; t++) {
                const short8 bh = *(const short8*)&BsH[(t*16 + arow)*40 + aq*8];
                const short8 bl = *(const short8*)&BsL[(t*16 + arow)*40 + aq*8];
                acc[t] = __builtin_amdgcn_mfma_f32_16x16x32_bf16(a, bh, acc[t], 0, 0, 0);
                acc[t] = __builtin_amdgcn_mfma_f32_16x16x32_bf16(a, bl, acc[t], 0, 0, 0);
            }
        }
    }
    __syncthreads();

    int dgc[4];
    #pragma unroll
    for (int r = 0; r < 4; r++) {
        int d = dgp[ng0 + 16*wv + aq*4 + r];
        dgc[r] = d > 199 ? 199 : d;
    }
    #pragma unroll
    for (int nt = 0; nt < 13; nt++) {
        const int col = nt*16 + arow;
        float s = 0.f;
        if (col < DH) {
            #pragma unroll
            for (int r = 0; r < 4; r++)
                s += fmaxf(acc[nt][r], 0.f) + degree_table[dgc[r]*DH + col];
        }
        s += __shfl_xor(s, 16, 64);
        s += __shfl_xor(s, 32, 64);
        if (lane < 16 && col < DH) atomicAdd(&part[col], s);
    }
    __syncthreads();
    if (tid < DH) unsafeAtomicAdd(&hsg[b*206 + tid], part[tid] * (1.0f/512.0f));
}

// ---------------------------------------------------------------------------
// Kernel 6: interaction mean over nodes -> hsg cols 200..205
// ---------------------------------------------------------------------------
__global__ __launch_bounds__(192) void inter_kernel(
    const float* __restrict__ i1, const float* __restrict__ i2,
    float* __restrict__ hsg1, float* __restrict__ hsg2)
{
    const int side = blockIdx.y;
    const float* it = side ? i2 : i1;
    float* hsg = side ? hsg2 : hsg1;
    const int b = blockIdx.x;
    __shared__ float red[192];
    const int tid = threadIdx.x;
    const int j = tid % 6, seg = tid / 6;
    float s = 0.0f;
    for (int n = seg*16; n < seg*16 + 16; n++)
        s += it[(size_t)b*NN*DI + n*DI + j];
    red[tid] = s;
    __syncthreads();
    if (tid < 6) {
        float tot = 0.0f;
        for (int sg2 = 0; sg2 < 32; sg2++) tot += red[sg2*6 + tid];
        hsg[b*206 + 200 + tid] = tot * (1.0f/512.0f);
    }
}

// ---------------------------------------------------------------------------
// Kernel 7: final MLP, one block per batch row
// ---------------------------------------------------------------------------
__global__ __launch_bounds__(256) void mlp_kernel(
    const float* __restrict__ hsg1, const float* __restrict__ hsg2,
    const float* __restrict__ W_f1, const float* __restrict__ b_f1,
    const float* __restrict__ W_f2, const float* __restrict__ b_f2,
    const float* __restrict__ W_f3, const float* __restrict__ b_f3,
    const float* __restrict__ W_f4, const float* __restrict__ b_f4,
    float* __restrict__ out)
{
    const int b = blockIdx.x;
    __shared__ float x[618];
    __shared__ float y1[400];
    __shared__ float y2[200];
    __shared__ float y3[100];
    __shared__ float red[256];
    const int tid = threadIdx.x;

    if (tid < 206) {
        const float a = hsg1[b*206 + tid], bb = hsg2[b*206 + tid];
        x[tid] = a; x[206 + tid] = bb; x[412 + tid] = a - bb;
    }
    __syncthreads();
    for (int c = tid; c < 400; c += 256) {
        float acc = b_f1[c];
        for (int k = 0; k < 618; k++) acc += x[k]*W_f1[(size_t)k*400 + c];
        y1[c] = fmaxf(acc, 0.0f);
    }
    __syncthreads();
    if (tid < 200) {
        float acc = b_f2[tid];
        for (int k = 0; k < 400; k++) acc += y1[k]*W_f2[k*200 + tid];
        y2[tid] = fmaxf(acc, 0.0f);
    }
    __syncthreads();
    if (tid < 100) {
        float acc = b_f3[tid];
        for (int k = 0; k < 200; k++) acc += y2[k]*W_f3[k*100 + tid];
        y3[tid] = fmaxf(acc, 0.0f);
    }
    __syncthreads();
    red[tid] = (tid < 100) ? y3[tid]*W_f4[tid] : 0.0f;
    __syncthreads();
    for (int s = 128; s > 0; s >>= 1) {
        if (tid < s) red[tid] += red[tid + s];
        __syncthreads();
    }
    if (tid == 0) out[b] = red[0] + b_f4[0];
}

// ---------------------------------------------------------------------------
extern "C" void kernel_launch(void* const* d_in, const int* in_sizes, int n_in,
                              void* d_out, int out_size, void* d_ws, size_t ws_size,
                              hipStream_t stream)
{
    const float* atom1  = (const float*)d_in[0];
    const float* atom2  = (const float*)d_in[1];
    const float* coords1= (const float*)d_in[2];
    const float* coords2= (const float*)d_in[3];
    const float* efeat1 = (const float*)d_in[4];
    const float* efeat2 = (const float*)d_in[5];
    const float* inter1 = (const float*)d_in[6];
    const float* inter2 = (const float*)d_in[7];
    const int*   esrc1  = (const int*)d_in[8];
    const int*   edst1  = (const int*)d_in[9];
    const int*   esrc2  = (const int*)d_in[10];
    const int*   edst2  = (const int*)d_in[11];
    const float* W_atom = (const float*)d_in[12];
    const float* W_edge = (const float*)d_in[13];
    const float* W_rbf  = (const float*)d_in[14];
    const float* b_rbf  = (const float*)d_in[15];
    const float* ln_g   = (const float*)d_in[16];
    const float* ln_b   = (const float*)d_in[17];
    const float* W_down = (const float*)d_in[18];
    const float* deg_tab= (const float*)d_in[19];
    const float* W_f1   = (const float*)d_in[20];
    const float* b_f1   = (const float*)d_in[21];
    const float* W_f2   = (const float*)d_in[22];
    const float* b_f2   = (const float*)d_in[23];
    const float* W_f3   = (const float*)d_in[24];
    const float* b_f3   = (const float*)d_in[25];
    const float* W_f4   = (const float*)d_in[26];
    const float* b_f4   = (const float*)d_in[27];
    float* out = (float*)d_out;

    // ---- workspace layout (~133 MB)
    float* ws = (float*)d_ws;
    const size_t HSZ = (size_t)BN*DH;              // per-side h floats
    float* h1  = ws;
    float* h2  = h1 + HSZ;
    // pool: max(feat 2*(EE+16)*32 shorts = 67.1 MB, bf16 pool 73.4 MB)
    short* pool = (short*)(h2 + HSZ);
    const size_t FSZ = (size_t)(EE+16)*32;
    short* featH1 = pool;
    short* featH2 = featH1 + FSZ;
    const size_t HB = (size_t)32*NN*224;           // 3,670,016 shorts
    short* hbH1 = pool;           short* hbL1 = hbH1 + HB;
    short* hbH2 = hbL1 + HB;      short* hbL2 = hbH2 + HB;
    short* hTH1 = hbL2 + HB;      short* hTL1 = hTH1 + HB;
    short* hTH2 = hTL1 + HB;      short* hTL2 = hTH2 + HB;
    short* cb1  = hTL2 + HB;      short* cb2  = cb1 + HB;
    size_t pool_sz = 2*FSZ > 10*HB ? 2*FSZ : 10*HB;
    short* after = pool + pool_sz;
    short* WTH = after;                            // [208][32]
    short* WTL = WTH + 208*32;
    short* WbTH = WTL + 208*32;                    // [208][448]
    short* WbTL = WbTH + 208*448;
    float* hsg1 = (float*)(WbTL + 208*448);
    float* hsg2 = hsg1 + (size_t)BB*206;
    int* deg1 = (int*)(hsg2 + (size_t)BB*206);
    int* deg2 = deg1 + BN;
    int* start1 = deg2 + BN;                       // BN+1 entries
    int* start2 = start1 + (BN+1);
    int* cursor1 = start2 + (BN+1);
    int* cursor2 = cursor1 + BN;
    int* rank1 = cursor2 + BN;
    int* rank2 = rank1 + EE;

    hipMemsetAsync(deg1, 0, 2*(size_t)BN*sizeof(int), stream);
    hipMemsetAsync(hsg1, 0, 2*(size_t)BB*206*sizeof(float), stream);

    node_kernel<<<dim3(BN/4, 2), 256, 0, stream>>>(
        atom1, atom2, W_atom, ln_g, ln_b, h1, h2);

    hist_kernel<<<EE/256, 256, 0, stream>>>(edst1, edst2, deg1, deg2);
    scan_kernel<<<2, 1024, 0, stream>>>(deg1, deg2, start1, start2, cursor1, cursor2);
    scatter_kernel<<<EE/256, 256, 0, stream>>>(edst1, edst2, cursor1, cursor2,
                                               rank1, rank2);

    featgen_kernel<<<dim3(EE/256, 2), 256, 0, stream>>>(
        efeat1, efeat2, esrc1, esrc2, edst1, edst2, coords1, coords2,
        rank1, rank2, featH1, featH2);

    prep_wt_kernel<<<(208*32 + 255)/256, 256, 0, stream>>>(
        W_edge, W_rbf, b_rbf, WTH, WTL);

    gather_mfma<<<dim3(BN/4, 2), 256, 0, stream>>>(
        featH1, featH2, start1, start2, WTH, WTL, ln_g, ln_b, h1, h2);

    prep_w_kernel<<<(208*448 + 255)/256, 256, 0, stream>>>(W_down, WbTH, WbTL);

    for (int half = 0; half < 2; half++) {
        cvt_kernel<<<dim3(HBN/64, 2), 256, 0, stream>>>(
            h1, h2, half, hbH1, hbL1, hbH2, hbL2, hTH1, hTL1, hTH2, hTL2);
        // dir0: c1 = softmax_rows(h1@h2^T) @ h2
        attn_kernel<<<dim3(NN/16, 32), 256, 0, stream>>>(
            hbH1, hbL1, hbH2, hbL2, hTH2, hTL2, cb1);
        // dir1: c2 = softmax_rows(h2@h1^T) @ h1
        attn_kernel<<<dim3(NN/16, 32), 256, 0, stream>>>(
            hbH2, hbL2, hbH1, hbL1, hTH1, hTL1, cb2);
        down_mfma<<<dim3(HBN/64, 2), 256, 0, stream>>>(
            hbH1, hbH2, cb1, cb2, deg1, deg2, WbTH, WbTL, deg_tab,
            hsg1, hsg2, half);
    }

    inter_kernel<<<dim3(BB, 2), 192, 0, stream>>>(inter1, inter2, hsg1, hsg2);

    mlp_kernel<<<BB, 256, 0, stream>>>(
        hsg1, hsg2, W_f1, b_f1, W_f2, b_f2, W_f3, b_f3, W_f4, b_f4, out);
}

// Round 12
// 1205.491 us; speedup vs baseline: 1.3485x; 1.3485x over previous
//
#include <hip/hip_runtime.h>
#include <cstddef>
#include <cstdint>

// Problem constants
#define BB   64
#define NN   512
#define BN   (BB*NN)          // 32768
#define HBN  16384            // nodes per half
#define EE   524288
#define DA   70
#define DE   14
#define DH   200
#define DI   6
#define T_SCALE 0.07071067811865475f   // sqrt(1/200)

typedef __attribute__((ext_vector_type(8))) short short8;
typedef __attribute__((ext_vector_type(4))) float f32x4;

__device__ __forceinline__ short f2bf(float x) {
    union { float f; unsigned u; } v; v.f = x;
    const unsigned r = v.u + 0x7FFFu + ((v.u >> 16) & 1u);   // RNE
    return (short)(r >> 16);
}
__device__ __forceinline__ float bf2f(short s) {
    union { unsigned u; float f; } v;
    v.u = ((unsigned)(unsigned short)s) << 16;
    return v.f;
}

// ---------------------------------------------------------------------------
// Kernel 1: per-node  h = layernorm(relu(atom @ W_atom))
// ---------------------------------------------------------------------------
__global__ __launch_bounds__(256) void node_kernel(
    const float* __restrict__ atom1, const float* __restrict__ atom2,
    const float* __restrict__ W_atom,
    const float* __restrict__ ln_g, const float* __restrict__ ln_b,
    float* __restrict__ h1, float* __restrict__ h2)
{
    const int side = blockIdx.y;
    const float* atom = side ? atom2 : atom1;
    float* h = side ? h2 : h1;
    const int node0 = blockIdx.x * 4;
    const int tid = threadIdx.x;

    __shared__ float arow[4][DA];
    __shared__ float vals[4][DH];

    for (int i = tid; i < 4*DA; i += 256) {
        const int n = i / DA, k = i % DA;
        arow[n][k] = atom[(size_t)(node0+n)*DA + k];
    }
    __syncthreads();

    if (tid < DH) {
        float a0 = 0.f, a1 = 0.f, a2 = 0.f, a3 = 0.f;
        #pragma unroll 7
        for (int k = 0; k < DA; k++) {
            const float w = W_atom[k*DH + tid];
            a0 += arow[0][k]*w; a1 += arow[1][k]*w;
            a2 += arow[2][k]*w; a3 += arow[3][k]*w;
        }
        vals[0][tid] = fmaxf(a0, 0.f);
        vals[1][tid] = fmaxf(a1, 0.f);
        vals[2][tid] = fmaxf(a2, 0.f);
        vals[3][tid] = fmaxf(a3, 0.f);
    }
    __syncthreads();

    const int wv = tid >> 6, lane = tid & 63;
    float v0 = vals[wv][lane];
    float v1 = vals[wv][64+lane];
    float v2 = vals[wv][128+lane];
    float v3 = (lane < 8) ? vals[wv][192+lane] : 0.0f;
    float s  = v0+v1+v2+v3;
    float s2 = v0*v0+v1*v1+v2*v2+v3*v3;
    #pragma unroll
    for (int off = 1; off < 64; off <<= 1) {
        s  += __shfl_xor(s,  off, 64);
        s2 += __shfl_xor(s2, off, 64);
    }
    const float mean = s * (1.0f/DH);
    const float var  = s2 * (1.0f/DH) - mean*mean;
    const float rstd = rsqrtf(var + 1e-5f);
    const size_t base = (size_t)(node0+wv)*DH;
    h[base + lane]       = ln_g[lane]     *(v0-mean)*rstd + ln_b[lane];
    h[base + 64 + lane]  = ln_g[64+lane]  *(v1-mean)*rstd + ln_b[64+lane];
    h[base + 128 + lane] = ln_g[128+lane] *(v2-mean)*rstd + ln_b[128+lane];
    if (lane < 8)
        h[base + 192 + lane] = ln_g[192+lane]*(v3-mean)*rstd + ln_b[192+lane];
}

// ---------------------------------------------------------------------------
// Counting sort by dst: hist -> scan(+sentinel) -> scatter (rank only)
// ---------------------------------------------------------------------------
__global__ __launch_bounds__(256) void hist_kernel(
    const int* __restrict__ edst1, const int* __restrict__ edst2,
    int* __restrict__ deg1, int* __restrict__ deg2)
{
    const int e = blockIdx.x*256 + threadIdx.x;
    atomicAdd(&deg1[edst1[e]], 1);
    atomicAdd(&deg2[edst2[e]], 1);
}

__global__ __launch_bounds__(1024) void scan_kernel(
    const int* __restrict__ deg1, const int* __restrict__ deg2,
    int* __restrict__ start1, int* __restrict__ start2,
    int* __restrict__ cursor1, int* __restrict__ cursor2)
{
    const int side = blockIdx.x;
    const int* deg   = side ? deg2 : deg1;
    int* start  = side ? start2 : start1;
    int* cursor = side ? cursor2 : cursor1;

    __shared__ int part[1024];
    const int t = threadIdx.x;
    const int base = t * 32;
    int local[32];
    int sum = 0;
    #pragma unroll
    for (int i = 0; i < 32; i++) { local[i] = deg[base+i]; sum += local[i]; }
    part[t] = sum;
    __syncthreads();
    for (int off = 1; off < 1024; off <<= 1) {
        int v = (t >= off) ? part[t-off] : 0;
        __syncthreads();
        part[t] += v;
        __syncthreads();
    }
    int run = part[t] - sum;   // exclusive
    #pragma unroll
    for (int i = 0; i < 32; i++) {
        start[base+i] = run;
        cursor[base+i] = run;
        run += local[i];
    }
    if (t == 1023) start[BN] = run;   // sentinel == EE
}

__global__ __launch_bounds__(256) void scatter_kernel(
    const int* __restrict__ edst1, const int* __restrict__ edst2,
    int* __restrict__ cursor1, int* __restrict__ cursor2,
    int* __restrict__ rank1, int* __restrict__ rank2)
{
    const int e = blockIdx.x*256 + threadIdx.x;
    {
        const int d = edst1[e];
        rank1[e] = atomicAdd(&cursor1[d], 1);
    }
    {
        const int d = edst2[e];
        rank2[e] = atomicAdd(&cursor2[d], 1);
    }
}

// ---------------------------------------------------------------------------
// featgen: per-edge feature row (rank-ordered) -> featH[rank][32] bf16
//   k 0..13 = ef, 14..29 = rbf, 30 = 1.0 (bias hook), 31 = 0
// ---------------------------------------------------------------------------
__global__ __launch_bounds__(256) void featgen_kernel(
    const float* __restrict__ efeat1, const float* __restrict__ efeat2,
    const int* __restrict__ esrc1, const int* __restrict__ esrc2,
    const int* __restrict__ edst1, const int* __restrict__ edst2,
    const float* __restrict__ coords1, const float* __restrict__ coords2,
    const int* __restrict__ rank1, const int* __restrict__ rank2,
    short* __restrict__ featH1, short* __restrict__ featH2)
{
    const int side = blockIdx.y;
    const float* ef     = side ? efeat2  : efeat1;
    const int*   esrc   = side ? esrc2   : esrc1;
    const int*   edst   = side ? edst2   : edst1;
    const float* coords = side ? coords2 : coords1;
    const int*   rank   = side ? rank2   : rank1;
    short* featH = side ? featH2 : featH1;

    const int e = blockIdx.x*256 + threadIdx.x;
    const int src = esrc[e], dst = edst[e];

    short f[32];
    #pragma unroll
    for (int k = 0; k < 14; k++) f[k] = f2bf(ef[(size_t)e*DE + k]);

    const float dx = coords[src*3+0] - coords[dst*3+0];
    const float dy = coords[src*3+1] - coords[dst*3+1];
    const float dz = coords[src*3+2] - coords[dst*3+2];
    const float dist = sqrtf(dx*dx + dy*dy + dz*dz + 1e-12f);
    #pragma unroll
    for (int k = 0; k < 16; k++) {
        const float t = 3.2f*dist - 1.0666666667f*(float)k;
        f[14+k] = f2bf(__expf(-t*t));
    }
    f[30] = f2bf(1.0f);
    f[31] = 0;

    short* out = featH + (size_t)rank[e]*32;
    #pragma unroll
    for (int q = 0; q < 4; q++)
        *(short8*)&out[q*8] = *(short8*)&f[q*8];
}

// ---------------------------------------------------------------------------
// featpad: zero the 16-row pad past EE so tail tiles read finite zeros
// ---------------------------------------------------------------------------
__global__ __launch_bounds__(256) void featpad_kernel(
    short* __restrict__ featH1, short* __restrict__ featH2)
{
    const int i = threadIdx.x;   // 16*32 = 512 shorts... use 256 threads x2
    featH1[(size_t)EE*32 + i] = 0;
    featH1[(size_t)EE*32 + 256 + i] = 0;
    featH2[(size_t)EE*32 + i] = 0;
    featH2[(size_t)EE*32 + 256 + i] = 0;
}

// ---------------------------------------------------------------------------
// prep_wt: build WT[208][32] hi/lo for the edge projection.
// ---------------------------------------------------------------------------
__global__ __launch_bounds__(256) void prep_wt_kernel(
    const float* __restrict__ W_edge, const float* __restrict__ W_rbf,
    const float* __restrict__ b_rbf,
    short* __restrict__ WTH, short* __restrict__ WTL)
{
    const int idx = blockIdx.x*256 + threadIdx.x;
    if (idx >= 208*32) return;
    const int c = idx >> 5, k = idx & 31;
    float v = 0.f;
    if (c < 100) {
        if (k < 14) v = W_edge[k*100 + c];
    } else if (c < 200) {
        const int cc = c - 100;
        if (k >= 14 && k < 30) v = W_rbf[(k-14)*100 + cc];
        else if (k == 30) v = b_rbf[cc];
    }
    const short hi = f2bf(v);
    WTH[idx] = hi;
    WTL[idx] = f2bf(v - bf2f(hi));
}

// ---------------------------------------------------------------------------
// gather_mfma v2: one WAVE per node (no segmentation, no atomics, no merge
// branches). W fragments staged in LDS once per block (shared); per-node
// column sums live in 13 registers/lane, reduced over aq at the end.
// Tail rows (>= deg) masked via rstd=0; feat has a zeroed 16-row pad.
// ---------------------------------------------------------------------------
__global__ __launch_bounds__(256) void gather_mfma(
    const short* __restrict__ featH1, const short* __restrict__ featH2,
    const int* __restrict__ start1, const int* __restrict__ start2,
    const short* __restrict__ WTH, const short* __restrict__ WTL,
    const float* __restrict__ ln_g, const float* __restrict__ ln_b,
    float* __restrict__ h1, float* __restrict__ h2)
{
    const int side = blockIdx.y;
    const short* feat = side ? featH2 : featH1;
    const int* start  = side ? start2 : start1;
    float* h = side ? h2 : h1;

    __shared__ short sWH[208*32];    // 13.3 KB
    __shared__ short sWL[208*32];    // 13.3 KB
    __shared__ float plane[4][216];

    const int tid = threadIdx.x;
    const int wv = tid >> 6, lane = tid & 63;
    const int arow = lane & 15, aq = lane >> 4;

    for (int f = tid; f < 832; f += 256) {
        *(short8*)&sWH[f*8] = *(const short8*)&WTH[f*8];
        *(short8*)&sWL[f*8] = *(const short8*)&WTL[f*8];
    }
    __syncthreads();

    const int node = blockIdx.x*4 + wv;
    const int st = __builtin_amdgcn_readfirstlane(start[node]);
    const int dg = __builtin_amdgcn_readfirstlane(start[node+1]) - st;

    float colacc[13];
    #pragma unroll
    for (int nt = 0; nt < 13; nt++) colacc[nt] = 0.f;
    float musum = 0.f;

    for (int t0 = 0; t0 < dg; t0 += 16) {
        const short8 a = *(const short8*)&feat[(size_t)(st + t0 + arow)*32 + aq*8];
        f32x4 acc[13];
        #pragma unroll
        for (int nt = 0; nt < 13; nt++) {
            const short8 wh = *(const short8*)&sWH[(nt*16 + arow)*32 + aq*8];
            const short8 wl = *(const short8*)&sWL[(nt*16 + arow)*32 + aq*8];
            acc[nt] = (f32x4){0.f,0.f,0.f,0.f};
            acc[nt] = __builtin_amdgcn_mfma_f32_16x16x32_bf16(a, wh, acc[nt], 0, 0, 0);
            acc[nt] = __builtin_amdgcn_mfma_f32_16x16x32_bf16(a, wl, acc[nt], 0, 0, 0);
        }
        // relu + per-row (per-edge) stats; row = t0 + aq*4 + r
        float sr[4] = {0.f,0.f,0.f,0.f}, s2r[4] = {0.f,0.f,0.f,0.f};
        #pragma unroll
        for (int nt = 0; nt < 13; nt++) {
            #pragma unroll
            for (int r = 0; r < 4; r++) {
                const float v = fmaxf(acc[nt][r], 0.f);
                acc[nt][r] = v;
                sr[r] += v; s2r[r] += v*v;
            }
        }
        #pragma unroll
        for (int off = 1; off < 16; off <<= 1) {
            #pragma unroll
            for (int r = 0; r < 4; r++) {
                sr[r]  += __shfl_xor(sr[r],  off, 64);
                s2r[r] += __shfl_xor(s2r[r], off, 64);
            }
        }
        #pragma unroll
        for (int r = 0; r < 4; r++) {
            const bool valid = (t0 + aq*4 + r) < dg;
            const float mean = sr[r] * (1.0f/DH);
            const float var  = s2r[r] * (1.0f/DH) - mean*mean;
            const float rs = rsqrtf(var + 1e-5f);
            const float rstd = valid ? rs : 0.f;
            musum += valid ? mean*rs : 0.f;
            #pragma unroll
            for (int nt = 0; nt < 13; nt++)
                colacc[nt] += rstd*acc[nt][r];
        }
    }

    // reduce over the 4 aq groups (rows partition)
    #pragma unroll
    for (int nt = 0; nt < 13; nt++) {
        colacc[nt] += __shfl_xor(colacc[nt], 16, 64);
        colacc[nt] += __shfl_xor(colacc[nt], 32, 64);
    }
    musum += __shfl_xor(musum, 16, 64);
    musum += __shfl_xor(musum, 32, 64);

    if (aq == 0) {
        #pragma unroll
        for (int nt = 0; nt < 13; nt++)
            plane[wv][nt*16 + arow] = colacc[nt];
    }
    // wave-internal LDS producer/consumer: same wave, in-order — no barrier

    const float dgf = (float)dg;
    const size_t base = (size_t)node * DH;
    h[base + lane]       += ln_g[lane]     *(plane[wv][lane]     - musum) + dgf*ln_b[lane];
    h[base + 64 + lane]  += ln_g[64+lane]  *(plane[wv][64+lane]  - musum) + dgf*ln_b[64+lane];
    h[base + 128 + lane] += ln_g[128+lane] *(plane[wv][128+lane] - musum) + dgf*ln_b[128+lane];
    if (lane < 8)
        h[base + 192 + lane] += ln_g[192+lane]*(plane[wv][192+lane] - musum) + dgf*ln_b[192+lane];
}

// ---------------------------------------------------------------------------
// cvt (per half): h fp32 -> hb hi/lo [16384][224] rows + hbT hi/lo [32][224][512]
// ---------------------------------------------------------------------------
__global__ __launch_bounds__(256) void cvt_kernel(
    const float* __restrict__ h1, const float* __restrict__ h2, const int half,
    short* __restrict__ hbH1, short* __restrict__ hbL1,
    short* __restrict__ hbH2, short* __restrict__ hbL2,
    short* __restrict__ hTH1, short* __restrict__ hTL1,
    short* __restrict__ hTH2, short* __restrict__ hTL2)
{
    const int side = blockIdx.y;
    const float* h = side ? h2 : h1;
    short* hbH = side ? hbH2 : hbH1;
    short* hbL = side ? hbL2 : hbL1;
    short* hTH = side ? hTH2 : hTH1;
    short* hTL = side ? hTL2 : hTL1;

    const int nl0 = blockIdx.x * 64;          // local node
    const int bl = nl0 >> 9, m0 = nl0 & 511;
    const int ng0 = half*HBN + nl0;

    __shared__ short tH[64][226];
    __shared__ short tL[64][226];
    const int tid = threadIdx.x;
    for (int i = tid; i < 64*224; i += 256) {
        const int r = i / 224, c = i - r*224;
        const float v = (c < DH) ? h[(size_t)(ng0+r)*DH + c] : 0.f;
        const short hi = f2bf(v);
        const short lo = f2bf(v - bf2f(hi));
        tH[r][c] = hi; tL[r][c] = lo;
        hbH[(size_t)(nl0+r)*224 + c] = hi;
        hbL[(size_t)(nl0+r)*224 + c] = lo;
    }
    __syncthreads();
    for (int i = tid; i < 224*64; i += 256) {
        const int c = i >> 6, m = i & 63;
        const size_t o = ((size_t)bl*224 + c)*NN + m0 + m;
        hTH[o] = tH[m][c];
        hTL[o] = tL[m][c];
    }
}

// ---------------------------------------------------------------------------
// prep_w: W_down[400][200] -> WbTHI/LO[208][448] (transposed, padded, split)
// ---------------------------------------------------------------------------
__global__ __launch_bounds__(256) void prep_w_kernel(
    const float* __restrict__ W_down,
    short* __restrict__ WbTHI, short* __restrict__ WbTLO)
{
    const int idx = blockIdx.x*256 + threadIdx.x;
    if (idx >= 208*448) return;
    const int c = idx / 448, kk = idx - c*448;
    float v = 0.f;
    if (c < 200) {
        if (kk < 200) v = W_down[(size_t)kk*DH + c];
        else if (kk >= 224 && kk < 424) v = W_down[(size_t)(200 + kk - 224)*DH + c];
    }
    const short hi = f2bf(v);
    WbTHI[idx] = hi;
    WbTLO[idx] = f2bf(v - bf2f(hi));
}

// ---------------------------------------------------------------------------
// Fused attention v3: 16 Q-rows per block, 4 waves split 32 key-tiles;
// K/V streamed from global (L2); 3 barriers per block.
// ---------------------------------------------------------------------------
__global__ __launch_bounds__(256, 4) void attn_kernel(
    const short* __restrict__ QH, const short* __restrict__ QL,
    const short* __restrict__ KH, const short* __restrict__ KL,
    const short* __restrict__ VTH, const short* __restrict__ VTL,
    short* __restrict__ cb)
{
    const int b = blockIdx.y;                 // half-local batch
    const int q0 = blockIdx.x * 16;
    const short* Qh = QH + (size_t)b*NN*224;
    const short* Ql = QL + (size_t)b*NN*224;
    const short* Kh = KH + (size_t)b*NN*224;
    const short* Kl = KL + (size_t)b*NN*224;
    const short* Vh = VTH + (size_t)b*224*NN;
    const short* Vl = VTL + (size_t)b*224*NN;

    __shared__ short pb[16*520];              // 16.3 KB P bf16
    __shared__ float sm_[4][16];
    __shared__ float ss_[4][16];

    const int tid = threadIdx.x;
    const int wv = tid >> 6, lane = tid & 63;
    const int arow = lane & 15, aq = lane >> 4;

    const int qrow = q0 + arow;
    short8 qfh[7], qfl[7];
    #pragma unroll
    for (int k = 0; k < 7; k++) {
        qfh[k] = *(const short8*)&Qh[(size_t)qrow*224 + k*32 + aq*8];
        qfl[k] = *(const short8*)&Ql[(size_t)qrow*224 + k*32 + aq*8];
    }

    f32x4 acc[8];
    #pragma unroll
    for (int t = 0; t < 8; t++) acc[t] = (f32x4){0.f,0.f,0.f,0.f};

    #pragma unroll
    for (int t = 0; t < 8; t++) {
        const size_t kb = (size_t)((wv*8 + t)*16 + arow)*224;
        #pragma unroll
        for (int k = 0; k < 7; k++) {
            const short8 bh = *(const short8*)&Kh[kb + k*32 + aq*8];
            const short8 bl = *(const short8*)&Kl[kb + k*32 + aq*8];
            acc[t] = __builtin_amdgcn_mfma_f32_16x16x32_bf16(qfh[k], bh, acc[t], 0, 0, 0);
            acc[t] = __builtin_amdgcn_mfma_f32_16x16x32_bf16(qfh[k], bl, acc[t], 0, 0, 0);
            acc[t] = __builtin_amdgcn_mfma_f32_16x16x32_bf16(qfl[k], bh, acc[t], 0, 0, 0);
        }
    }

    float mr[4], sr[4], iv[4];
    #pragma unroll
    for (int r = 0; r < 4; r++) {
        float m = -1e30f;
        #pragma unroll
        for (int t = 0; t < 8; t++) {
            acc[t][r] *= T_SCALE;
            m = fmaxf(m, acc[t][r]);
        }
        m = fmaxf(m, __shfl_xor(m, 1, 64));
        m = fmaxf(m, __shfl_xor(m, 2, 64));
        m = fmaxf(m, __shfl_xor(m, 4, 64));
        m = fmaxf(m, __shfl_xor(m, 8, 64));
        mr[r] = m;
    }
    if (arow == 0) {
        #pragma unroll
        for (int r = 0; r < 4; r++) sm_[wv][aq*4+r] = mr[r];
    }
    __syncthreads();
    #pragma unroll
    for (int r = 0; r < 4; r++) {
        const int row = aq*4 + r;
        const float M = fmaxf(fmaxf(sm_[0][row], sm_[1][row]),
                              fmaxf(sm_[2][row], sm_[3][row]));
        float s = 0.f;
        #pragma unroll
        for (int t = 0; t < 8; t++) {
            const float e = __expf(acc[t][r] - M);
            acc[t][r] = e;
            s += e;
        }
        s += __shfl_xor(s, 1, 64);
        s += __shfl_xor(s, 2, 64);
        s += __shfl_xor(s, 4, 64);
        s += __shfl_xor(s, 8, 64);
        sr[r] = s;
    }
    if (arow == 0) {
        #pragma unroll
        for (int r = 0; r < 4; r++) ss_[wv][aq*4+r] = sr[r];
    }
    __syncthreads();
    #pragma unroll
    for (int r = 0; r < 4; r++) {
        const int row = aq*4 + r;
        iv[r] = 1.0f / (ss_[0][row] + ss_[1][row] + ss_[2][row] + ss_[3][row]);
    }

    #pragma unroll
    for (int t = 0; t < 8; t++) {
        const int col = (wv*8 + t)*16 + arow;
        #pragma unroll
        for (int r = 0; r < 4; r++)
            pb[(aq*4 + r)*520 + col] = f2bf(acc[t][r] * iv[r]);
    }
    __syncthreads();

    const int nbase = (wv == 0) ? 0 : 3*wv + 1;
    const int ncnt  = (wv == 0) ? 4 : 3;
    f32x4 pacc[4];
    #pragma unroll
    for (int t = 0; t < 4; t++) pacc[t] = (f32x4){0.f,0.f,0.f,0.f};

    for (int k0 = 0; k0 < NN; k0 += 32) {
        const short8 a = *(const short8*)&pb[arow*520 + k0 + aq*8];
        #pragma unroll
        for (int t = 0; t < 4; t++) {
            if (t < ncnt) {
                const size_t vb = (size_t)((nbase+t)*16 + arow)*NN + k0 + aq*8;
                const short8 bh = *(const short8*)&Vh[vb];
                const short8 bl = *(const short8*)&Vl[vb];
                pacc[t] = __builtin_amdgcn_mfma_f32_16x16x32_bf16(a, bh, pacc[t], 0, 0, 0);
                pacc[t] = __builtin_amdgcn_mfma_f32_16x16x32_bf16(a, bl, pacc[t], 0, 0, 0);
            }
        }
    }

    #pragma unroll
    for (int t = 0; t < 4; t++) {
        if (t < ncnt) {
            const int col = (nbase+t)*16 + arow;
            #pragma unroll
            for (int r = 0; r < 4; r++) {
                const int row = q0 + aq*4 + r;
                const short v = (col < DH) ? f2bf(pacc[t][r]) : (short)0;
                cb[((size_t)b*NN + row)*224 + col] = v;
            }
        }
    }
    if (wv == 3) {
        const int col = 208 + arow;
        #pragma unroll
        for (int r = 0; r < 4; r++) {
            const int row = q0 + aq*4 + r;
            cb[((size_t)b*NN + row)*224 + col] = 0;
        }
    }
}

// ---------------------------------------------------------------------------
// down (per half, MFMA, split-W): relu([hb|cb] @ W_down) + degree_table -> hsg
// ---------------------------------------------------------------------------
__global__ __launch_bounds__(256) void down_mfma(
    const short* __restrict__ hbH1, const short* __restrict__ hbH2,
    const short* __restrict__ cb1, const short* __restrict__ cb2,
    const int* __restrict__ deg1, const int* __restrict__ deg2,
    const short* __restrict__ WbTH, const short* __restrict__ WbTL,
    const float* __restrict__ degree_table,
    float* __restrict__ hsg1, float* __restrict__ hsg2, const int half)
{
    const int side = blockIdx.y;
    const short* X0 = side ? hbH2 : hbH1;
    const short* X1 = side ? cb2 : cb1;
    const int*   dgp = side ? deg2 : deg1;
    float* hsg = side ? hsg2 : hsg1;

    const int nl0 = blockIdx.x * 64;
    const int ng0 = half*HBN + nl0;
    const int b = ng0 >> 9;

    __shared__ short As[64*40];
    __shared__ short BsH[208*40];
    __shared__ short BsL[208*40];
    __shared__ float part[208];

    const int tid = threadIdx.x;
    const int wv = tid >> 6, lane = tid & 63;
    const int arow = lane & 15, aq = lane >> 4;

    if (tid < 208) part[tid] = 0.f;

    f32x4 acc[13];
    #pragma unroll
    for (int t = 0; t < 13; t++) acc[t] = (f32x4){0.f,0.f,0.f,0.f};

    const int sr = tid >> 2, sc = (tid & 3) * 8;

    for (int phase = 0; phase < 2; phase++) {
        const short* X = phase ? X1 : X0;
        for (int k0 = 0; k0 < 224; k0 += 32) {
            __syncthreads();
            *(short8*)&As[sr*40 + sc] =
                *(const short8*)&X[(size_t)(nl0+sr)*224 + k0 + sc];
            const int kkg = phase*224 + k0;
            #pragma unroll
            for (int pass = 0; pass < 4; pass++) {
                const int f = pass*256 + tid;
                if (f < 832) {
                    const int d = f >> 2, cc = (f & 3) * 8;
                    *(short8*)&BsH[d*40 + cc] = *(const short8*)&WbTH[(size_t)d*448 + kkg + cc];
                    *(short8*)&BsL[d*40 + cc] = *(const short8*)&WbTL[(size_t)d*448 + kkg + cc];
                }
            }
            __syncthreads();
            const short8 a = *(const short8*)&As[(16*wv + arow)*40 + aq*8];
            #pragma unroll
            for (int t = 0; t < 13; t++) {
                const short8 bh = *(const short8*)&BsH[(t*16 + arow)*40 + aq*8];
                const short8 bl = *(const short8*)&BsL[(t*16 + arow)*40 + aq*8];
                acc[t] = __builtin_amdgcn_mfma_f32_16x16x32_bf16(a, bh, acc[t], 0, 0, 0);
                acc[t] = __builtin_amdgcn_mfma_f32_16x16x32_bf16(a, bl, acc[t], 0, 0, 0);
            }
        }
    }
    __syncthreads();

    int dgc[4];
    #pragma unroll
    for (int r = 0; r < 4; r++) {
        int d = dgp[ng0 + 16*wv + aq*4 + r];
        dgc[r] = d > 199 ? 199 : d;
    }
    #pragma unroll
    for (int nt = 0; nt < 13; nt++) {
        const int col = nt*16 + arow;
        float s = 0.f;
        if (col < DH) {
            #pragma unroll
            for (int r = 0; r < 4; r++)
                s += fmaxf(acc[nt][r], 0.f) + degree_table[dgc[r]*DH + col];
        }
        s += __shfl_xor(s, 16, 64);
        s += __shfl_xor(s, 32, 64);
        if (lane < 16 && col < DH) atomicAdd(&part[col], s);
    }
    __syncthreads();
    if (tid < DH) unsafeAtomicAdd(&hsg[b*206 + tid], part[tid] * (1.0f/512.0f));
}

// ---------------------------------------------------------------------------
// Kernel 6: interaction mean over nodes -> hsg cols 200..205
// ---------------------------------------------------------------------------
__global__ __launch_bounds__(192) void inter_kernel(
    const float* __restrict__ i1, const float* __restrict__ i2,
    float* __restrict__ hsg1, float* __restrict__ hsg2)
{
    const int side = blockIdx.y;
    const float* it = side ? i2 : i1;
    float* hsg = side ? hsg2 : hsg1;
    const int b = blockIdx.x;
    __shared__ float red[192];
    const int tid = threadIdx.x;
    const int j = tid % 6, seg = tid / 6;
    float s = 0.0f;
    for (int n = seg*16; n < seg*16 + 16; n++)
        s += it[(size_t)b*NN*DI + n*DI + j];
    red[tid] = s;
    __syncthreads();
    if (tid < 6) {
        float tot = 0.0f;
        for (int sg2 = 0; sg2 < 32; sg2++) tot += red[sg2*6 + tid];
        hsg[b*206 + 200 + tid] = tot * (1.0f/512.0f);
    }
}

// ---------------------------------------------------------------------------
// Kernel 7: final MLP, one block per batch row
// ---------------------------------------------------------------------------
__global__ __launch_bounds__(256) void mlp_kernel(
    const float* __restrict__ hsg1, const float* __restrict__ hsg2,
    const float* __restrict__ W_f1, const float* __restrict__ b_f1,
    const float* __restrict__ W_f2, const float* __restrict__ b_f2,
    const float* __restrict__ W_f3, const float* __restrict__ b_f3,
    const float* __restrict__ W_f4, const float* __restrict__ b_f4,
    float* __restrict__ out)
{
    const int b = blockIdx.x;
    __shared__ float x[618];
    __shared__ float y1[400];
    __shared__ float y2[200];
    __shared__ float y3[100];
    __shared__ float red[256];
    const int tid = threadIdx.x;

    if (tid < 206) {
        const float a = hsg1[b*206 + tid], bb = hsg2[b*206 + tid];
        x[tid] = a; x[206 + tid] = bb; x[412 + tid] = a - bb;
    }
    __syncthreads();
    for (int c = tid; c < 400; c += 256) {
        float acc = b_f1[c];
        for (int k = 0; k < 618; k++) acc += x[k]*W_f1[(size_t)k*400 + c];
        y1[c] = fmaxf(acc, 0.0f);
    }
    __syncthreads();
    if (tid < 200) {
        float acc = b_f2[tid];
        for (int k = 0; k < 400; k++) acc += y1[k]*W_f2[k*200 + tid];
        y2[tid] = fmaxf(acc, 0.0f);
    }
    __syncthreads();
    if (tid < 100) {
        float acc = b_f3[tid];
        for (int k = 0; k < 200; k++) acc += y2[k]*W_f3[k*100 + tid];
        y3[tid] = fmaxf(acc, 0.0f);
    }
    __syncthreads();
    red[tid] = (tid < 100) ? y3[tid]*W_f4[tid] : 0.0f;
    __syncthreads();
    for (int s = 128; s > 0; s >>= 1) {
        if (tid < s) red[tid] += red[tid + s];
        __syncthreads();
    }
    if (tid == 0) out[b] = red[0] + b_f4[0];
}

// ---------------------------------------------------------------------------
extern "C" void kernel_launch(void* const* d_in, const int* in_sizes, int n_in,
                              void* d_out, int out_size, void* d_ws, size_t ws_size,
                              hipStream_t stream)
{
    const float* atom1  = (const float*)d_in[0];
    const float* atom2  = (const float*)d_in[1];
    const float* coords1= (const float*)d_in[2];
    const float* coords2= (const float*)d_in[3];
    const float* efeat1 = (const float*)d_in[4];
    const float* efeat2 = (const float*)d_in[5];
    const float* inter1 = (const float*)d_in[6];
    const float* inter2 = (const float*)d_in[7];
    const int*   esrc1  = (const int*)d_in[8];
    const int*   edst1  = (const int*)d_in[9];
    const int*   esrc2  = (const int*)d_in[10];
    const int*   edst2  = (const int*)d_in[11];
    const float* W_atom = (const float*)d_in[12];
    const float* W_edge = (const float*)d_in[13];
    const float* W_rbf  = (const float*)d_in[14];
    const float* b_rbf  = (const float*)d_in[15];
    const float* ln_g   = (const float*)d_in[16];
    const float* ln_b   = (const float*)d_in[17];
    const float* W_down = (const float*)d_in[18];
    const float* deg_tab= (const float*)d_in[19];
    const float* W_f1   = (const float*)d_in[20];
    const float* b_f1   = (const float*)d_in[21];
    const float* W_f2   = (const float*)d_in[22];
    const float* b_f2   = (const float*)d_in[23];
    const float* W_f3   = (const float*)d_in[24];
    const float* b_f3   = (const float*)d_in[25];
    const float* W_f4   = (const float*)d_in[26];
    const float* b_f4   = (const float*)d_in[27];
    float* out = (float*)d_out;

    // ---- workspace layout (~133 MB)
    float* ws = (float*)d_ws;
    const size_t HSZ = (size_t)BN*DH;              // per-side h floats
    float* h1  = ws;
    float* h2  = h1 + HSZ;
    // pool: max(feat 2*(EE+16)*32 shorts, bf16 pool 10*HB shorts)
    short* pool = (short*)(h2 + HSZ);
    const size_t FSZ = (size_t)(EE+16)*32;
    short* featH1 = pool;
    short* featH2 = featH1 + FSZ;
    const size_t HB = (size_t)32*NN*224;           // 3,670,016 shorts
    short* hbH1 = pool;           short* hbL1 = hbH1 + HB;
    short* hbH2 = hbL1 + HB;      short* hbL2 = hbH2 + HB;
    short* hTH1 = hbL2 + HB;      short* hTL1 = hTH1 + HB;
    short* hTH2 = hTL1 + HB;      short* hTL2 = hTH2 + HB;
    short* cb1  = hTL2 + HB;      short* cb2  = cb1 + HB;
    size_t pool_sz = 2*FSZ > 10*HB ? 2*FSZ : 10*HB;
    short* after = pool + pool_sz;
    short* WTH = after;                            // [208][32]
    short* WTL = WTH + 208*32;
    short* WbTH = WTL + 208*32;                    // [208][448]
    short* WbTL = WbTH + 208*448;
    float* hsg1 = (float*)(WbTL + 208*448);
    float* hsg2 = hsg1 + (size_t)BB*206;
    int* deg1 = (int*)(hsg2 + (size_t)BB*206);
    int* deg2 = deg1 + BN;
    int* start1 = deg2 + BN;                       // BN+1 entries
    int* start2 = start1 + (BN+1);
    int* cursor1 = start2 + (BN+1);
    int* cursor2 = cursor1 + BN;
    int* rank1 = cursor2 + BN;
    int* rank2 = rank1 + EE;

    hipMemsetAsync(deg1, 0, 2*(size_t)BN*sizeof(int), stream);
    hipMemsetAsync(hsg1, 0, 2*(size_t)BB*206*sizeof(float), stream);

    node_kernel<<<dim3(BN/4, 2), 256, 0, stream>>>(
        atom1, atom2, W_atom, ln_g, ln_b, h1, h2);

    hist_kernel<<<EE/256, 256, 0, stream>>>(edst1, edst2, deg1, deg2);
    scan_kernel<<<2, 1024, 0, stream>>>(deg1, deg2, start1, start2, cursor1, cursor2);
    scatter_kernel<<<EE/256, 256, 0, stream>>>(edst1, edst2, cursor1, cursor2,
                                               rank1, rank2);

    featgen_kernel<<<dim3(EE/256, 2), 256, 0, stream>>>(
        efeat1, efeat2, esrc1, esrc2, edst1, edst2, coords1, coords2,
        rank1, rank2, featH1, featH2);
    featpad_kernel<<<1, 256, 0, stream>>>(featH1, featH2);

    prep_wt_kernel<<<(208*32 + 255)/256, 256, 0, stream>>>(
        W_edge, W_rbf, b_rbf, WTH, WTL);

    gather_mfma<<<dim3(BN/4, 2), 256, 0, stream>>>(
        featH1, featH2, start1, start2, WTH, WTL, ln_g, ln_b, h1, h2);

    prep_w_kernel<<<(208*448 + 255)/256, 256, 0, stream>>>(W_down, WbTH, WbTL);

    for (int half = 0; half < 2; half++) {
        cvt_kernel<<<dim3(HBN/64, 2), 256, 0, stream>>>(
            h1, h2, half, hbH1, hbL1, hbH2, hbL2, hTH1, hTL1, hTH2, hTL2);
        // dir0: c1 = softmax_rows(h1@h2^T) @ h2
        attn_kernel<<<dim3(NN/16, 32), 256, 0, stream>>>(
            hbH1, hbL1, hbH2, hbL2, hTH2, hTL2, cb1);
        // dir1: c2 = softmax_rows(h2@h1^T) @ h1
        attn_kernel<<<dim3(NN/16, 32), 256, 0, stream>>>(
            hbH2, hbL2, hbH1, hbL1, hTH1, hTL1, cb2);
        down_mfma<<<dim3(HBN/64, 2), 256, 0, stream>>>(
            hbH1, hbH2, cb1, cb2, deg1, deg2, WbTH, WbTL, deg_tab,
            hsg1, hsg2, half);
    }

    inter_kernel<<<dim3(BB, 2), 192, 0, stream>>>(inter1, inter2, hsg1, hsg2);

    mlp_kernel<<<BB, 256, 0, stream>>>(
        hsg1, hsg2, W_f1, b_f1, W_f2, b_f2, W_f3, b_f3, W_f4, b_f4, out);
}